// Round 1
// baseline (1129.987 us; speedup 1.0000x reference)
//
#include <hip/hip_runtime.h>
#include <math.h>

#define B 16
#define N 20000
#define H 640
#define A 128
#define LN_EPS 1e-5f
#define SCALE 0.08838834764831843f  // 128^-0.5

// ---------------------------------------------------------------------------
// Kernel 1: qk[b][h] = SCALE * sum_a Wk[a][h] * (sum_h' Wq[a][h'] * pos[b][h'])
// ---------------------------------------------------------------------------
__global__ __launch_bounds__(256) void qk_kernel(
    const float* __restrict__ pos, const float* __restrict__ Wq,
    const float* __restrict__ Wk, float* __restrict__ qk) {
  int b = blockIdx.x;
  __shared__ float sp[H];
  __shared__ float sq[A];
  for (int i = threadIdx.x; i < H; i += 256) sp[i] = pos[b * H + i];
  __syncthreads();
  if (threadIdx.x < A) {
    int a = threadIdx.x;
    const float* wr = Wq + (size_t)a * H;
    float acc = 0.f;
    for (int h = 0; h < H; h++) acc += wr[h] * sp[h];
    sq[a] = acc;
  }
  __syncthreads();
  for (int h = threadIdx.x; h < H; h += 256) {
    float acc = 0.f;
    for (int a = 0; a < A; a++) acc += Wk[(size_t)a * H + h] * sq[a];
    qk[b * H + h] = acc * SCALE;
  }
}

// ---------------------------------------------------------------------------
// Kernel 2: single-pass online-softmax weighted accumulation of gene_hiddens.
// One wave = one online-softmax state; 4 waves/block combined in LDS; one
// (m, l, o[640]) partial per block written to workspace.
// Lane i owns elements {2i+128k, 2i+1+128k : k=0..4} of each 640-float row
// (float2 loads, perfectly coalesced: 64 lanes x 8B contiguous per k).
// ---------------------------------------------------------------------------
__global__ __launch_bounds__(256) void pass1_kernel(
    const float* __restrict__ gh, const float* __restrict__ qk,
    float* __restrict__ pm, float* __restrict__ pl, float* __restrict__ po,
    int blocks_per_b) {
  int b = blockIdx.x / blocks_per_b;
  int blk = blockIdx.x - b * blocks_per_b;
  int wid = threadIdx.x >> 6;
  int lane = threadIdx.x & 63;
  int w = blk * 4 + wid;          // global wave index within batch b
  int nw = blocks_per_b * 4;      // total waves per batch

  const float2* qk2 = (const float2*)(qk + b * H);
  float2 qv[5];
#pragma unroll
  for (int k = 0; k < 5; k++) qv[k] = qk2[lane + 64 * k];

  const float2* ghb = (const float2*)(gh + (size_t)b * N * H);
  float m = -INFINITY, l = 0.f;
  float o[10];
#pragma unroll
  for (int k = 0; k < 10; k++) o[k] = 0.f;

  for (int n = w; n < N; n += nw) {
    const float2* row = ghb + (size_t)n * (H / 2);
    float2 hv[5];
#pragma unroll
    for (int k = 0; k < 5; k++) hv[k] = row[lane + 64 * k];
    float dot = 0.f;
#pragma unroll
    for (int k = 0; k < 5; k++) dot += hv[k].x * qv[k].x + hv[k].y * qv[k].y;
#pragma unroll
    for (int off = 32; off >= 1; off >>= 1) dot += __shfl_xor(dot, off);
    // dot is the full (already-scaled) score, identical on all 64 lanes
    float mn = fmaxf(m, dot);
    float alpha = __expf(m - mn);   // exp(-inf)=0 on first iteration
    float wt = __expf(dot - mn);
    l = l * alpha + wt;
#pragma unroll
    for (int k = 0; k < 5; k++) {
      o[2 * k]     = o[2 * k] * alpha     + wt * hv[k].x;
      o[2 * k + 1] = o[2 * k + 1] * alpha + wt * hv[k].y;
    }
    m = mn;
  }

  // combine the 4 wave states within the block
  __shared__ float wm[4], wl[4];
  __shared__ float wo[4][H];
  if (lane == 0) { wm[wid] = m; wl[wid] = l; }
#pragma unroll
  for (int k = 0; k < 5; k++) {
    wo[wid][2 * lane + 128 * k]     = o[2 * k];
    wo[wid][2 * lane + 128 * k + 1] = o[2 * k + 1];
  }
  __syncthreads();
  float M = fmaxf(fmaxf(wm[0], wm[1]), fmaxf(wm[2], wm[3]));
  float e0 = __expf(wm[0] - M), e1 = __expf(wm[1] - M);
  float e2 = __expf(wm[2] - M), e3 = __expf(wm[3] - M);
  int idx = b * blocks_per_b + blk;
  for (int e = threadIdx.x; e < H; e += 256) {
    po[(size_t)idx * H + e] =
        wo[0][e] * e0 + wo[1][e] * e1 + wo[2][e] * e2 + wo[3][e] * e3;
  }
  if (threadIdx.x == 0) {
    pm[idx] = M;
    pl[idx] = wl[0] * e0 + wl[1] * e1 + wl[2] * e2 + wl[3] * e3;
  }
}

// ---------------------------------------------------------------------------
// Kernel 3: combine partials -> s[640]; pooled = Wv @ s; LayerNorm -> out.
// One block per batch, 640 threads (thread = one hidden/output index).
// ---------------------------------------------------------------------------
__device__ __forceinline__ float block_reduce_640(float v, float* red) {
  int lane = threadIdx.x & 63, wid = threadIdx.x >> 6;
#pragma unroll
  for (int off = 32; off >= 1; off >>= 1) v += __shfl_xor(v, off);
  __syncthreads();              // protect red[] from any previous use
  if (lane == 0) red[wid] = v;
  __syncthreads();
  float t = 0.f;
#pragma unroll
  for (int j = 0; j < 10; j++) t += red[j];
  return t;
}

__global__ __launch_bounds__(640) void finalize_kernel(
    const float* __restrict__ pm, const float* __restrict__ pl,
    const float* __restrict__ po, const float* __restrict__ Wv,
    const float* __restrict__ gamma, const float* __restrict__ beta,
    float* __restrict__ out, int blocks_per_b) {
  int b = blockIdx.x;
  int tid = threadIdx.x;  // 0..639
  __shared__ float sh[H];
  __shared__ float red[16];

  float M = -INFINITY;
  for (int j = 0; j < blocks_per_b; j++) M = fmaxf(M, pm[b * blocks_per_b + j]);
  float L = 0.f;
  for (int j = 0; j < blocks_per_b; j++)
    L += pl[b * blocks_per_b + j] * __expf(pm[b * blocks_per_b + j] - M);
  float invL = 1.f / L;

  float s = 0.f;
  for (int j = 0; j < blocks_per_b; j++) {
    s += po[(size_t)(b * blocks_per_b + j) * H + tid] *
         __expf(pm[b * blocks_per_b + j] - M);
  }
  sh[tid] = s * invL;
  __syncthreads();

  // pooled[tid] = Wv[tid, :] . sh   (Wv is 1.6 MB -> L2-resident)
  const float* wrow = Wv + (size_t)tid * H;
  float acc = 0.f;
  for (int h = 0; h < H; h++) acc += wrow[h] * sh[h];

  // LayerNorm over the 640 pooled values
  float mu = block_reduce_640(acc, red) * (1.f / H);
  float d = acc - mu;
  float var = block_reduce_640(d * d, red) * (1.f / H);
  out[b * H + tid] = d * rsqrtf(var + LN_EPS) * gamma[tid] + beta[tid];
}

// ---------------------------------------------------------------------------
extern "C" void kernel_launch(void* const* d_in, const int* in_sizes, int n_in,
                              void* d_out, int out_size, void* d_ws, size_t ws_size,
                              hipStream_t stream) {
  const float* gh    = (const float*)d_in[0];  // [16,20000,640]
  const float* pos   = (const float*)d_in[1];  // [16,640]
  const float* Wq    = (const float*)d_in[2];  // [128,640]
  const float* Wk    = (const float*)d_in[3];  // [128,640]
  const float* Wv    = (const float*)d_in[4];  // [640,640]
  const float* gamma = (const float*)d_in[5];  // [640]
  const float* beta  = (const float*)d_in[6];  // [640]
  float* out = (float*)d_out;
  float* ws = (float*)d_ws;

  int blocks_per_b = 64;  // 64 blocks x 4 waves = 256 waves/batch, ~78 rows/wave
  while (blocks_per_b > 1 &&
         (size_t)(B * H + 2 * B * 64 + B * blocks_per_b * H) * 4 > ws_size)
    blocks_per_b >>= 1;

  float* qk = ws;                         // B*H      = 10240 floats
  float* pm = ws + B * H;                 // B*64     = 1024 floats (max)
  float* pl = pm + B * 64;                // B*64     = 1024 floats (max)
  float* po = pl + B * 64;                // B*blocks_per_b*H floats

  qk_kernel<<<B, 256, 0, stream>>>(pos, Wq, Wk, qk);
  pass1_kernel<<<B * blocks_per_b, 256, 0, stream>>>(gh, qk, pm, pl, po,
                                                     blocks_per_b);
  finalize_kernel<<<B, 640, 0, stream>>>(pm, pl, po, Wv, gamma, beta, out,
                                         blocks_per_b);
}